// Round 3
// baseline (205.200 us; speedup 1.0000x reference)
//
#include <hip/hip_runtime.h>
#include <hip/hip_bf16.h>

#define N_NODES 100000
#define HIDDEN 128
#define N_ARCS 1000000

typedef __attribute__((ext_vector_type(8))) short bf16x8;
typedef __attribute__((ext_vector_type(4))) float f32x4;

__device__ __forceinline__ unsigned short f2bf(float v) {
    union { float f; unsigned ui; } c; c.f = v;
    unsigned lsb = (c.ui >> 16) & 1;
    return (unsigned short)((c.ui + 0x7fffu + lsb) >> 16);
}

__device__ __forceinline__ unsigned pk2(float lo, float hi) {
    __hip_bfloat162 b = __float22bfloat162_rn(make_float2(lo, hi));
    union { __hip_bfloat162 b; unsigned u; } c; c.b = b; return c.u;
}

__device__ __forceinline__ uint4 pack8(const float4 a, const float4 b) {
    uint4 r;
    r.x = pk2(a.x, a.y);
    r.y = pk2(a.z, a.w);
    r.z = pk2(b.x, b.y);
    r.w = pk2(b.z, b.w);
    return r;
}

// UV[node][0:128] = z @ W1[:,:128]^T + b1 ; UV[node][128:256] = z @ W1[:,128:]^T
// fp32 in, bf16 LDS/MFMA, bf16 UV out. One block per 128-row tile; A staged once,
// both 128-col halves of W1 looped internally.
__global__ __launch_bounds__(256) void gemm_uv(const float* __restrict__ z,
                                               const float* __restrict__ W1,
                                               const float* __restrict__ b1,
                                               unsigned short* __restrict__ UV) {
    __shared__ unsigned short As[128 * 128];
    __shared__ unsigned short Bs[128 * 128];
    const int tid = threadIdx.x;
    const int m0 = blockIdx.x * 128;

    // Stage A (z tile, fp32 -> bf16 packed cvt), 16B granules, 4-bit XOR swizzle:
    // slot(row, g) = row*16 + (g ^ (row & 15))  -> fragment reads are 2-way-free.
    #pragma unroll
    for (int it = 0; it < 8; it++) {
        int i = tid + it * 256;
        int row = i >> 4, g = i & 15;
        int node = m0 + row;
        uint4 p = make_uint4(0u, 0u, 0u, 0u);
        if (node < N_NODES) {
            const float4* s = (const float4*)(z + (long)node * 128 + g * 8);
            p = pack8(s[0], s[1]);
        }
        ((uint4*)As)[row * 16 + (g ^ (row & 15))] = p;
    }

    const int lane = tid & 63;
    const int wave = tid >> 6;
    const int wm = (wave & 1) * 64;
    const int wn = (wave >> 1) * 64;
    const int l16 = lane & 15;
    const int quad = lane >> 4;

    for (int c0 = 0; c0 <= 128; c0 += 128) {
        // Stage B: Bs[n][k] = W1[n][c0+k] (bf16, same swizzle).
        #pragma unroll
        for (int it = 0; it < 8; it++) {
            int i = tid + it * 256;
            int row = i >> 4, g = i & 15;
            const float4* s = (const float4*)(W1 + (long)row * 256 + c0 + g * 8);
            ((uint4*)Bs)[row * 16 + (g ^ (row & 15))] = pack8(s[0], s[1]);
        }
        __syncthreads();

        f32x4 acc[4][4] = {};
        #pragma unroll
        for (int kk = 0; kk < 128; kk += 32) {
            const int gbase = (kk >> 3) + quad;
            bf16x8 a[4], b[4];
            #pragma unroll
            for (int mt = 0; mt < 4; mt++) {
                int row = wm + mt * 16 + l16;
                a[mt] = *(const bf16x8*)&As[row * 128 + ((gbase ^ l16) << 3)];
            }
            #pragma unroll
            for (int nt = 0; nt < 4; nt++) {
                int row = wn + nt * 16 + l16;
                b[nt] = *(const bf16x8*)&Bs[row * 128 + ((gbase ^ l16) << 3)];
            }
            #pragma unroll
            for (int mt = 0; mt < 4; mt++)
                #pragma unroll
                for (int nt = 0; nt < 4; nt++)
                    acc[mt][nt] = __builtin_amdgcn_mfma_f32_16x16x32_bf16(
                        a[mt], b[nt], acc[mt][nt], 0, 0, 0);
        }

        // C/D: col = lane&15, row = quad*4 + reg. Fold b1 into the U half.
        #pragma unroll
        for (int nt = 0; nt < 4; nt++) {
            int gcol = c0 + wn + nt * 16 + l16;
            float bias = (c0 == 0) ? b1[gcol] : 0.0f;
            #pragma unroll
            for (int mt = 0; mt < 4; mt++) {
                #pragma unroll
                for (int r = 0; r < 4; r++) {
                    int grow = m0 + wm + mt * 16 + quad * 4 + r;
                    if (grow < N_NODES)
                        UV[(long)grow * 256 + gcol] = f2bf(acc[mt][nt][r] + bias);
                }
            }
        }
        __syncthreads();   // all waves done with Bs before restaging
    }
}

// One arc per 16-lane quarter-wave, 2 arcs per quarter per iteration.
// 16 lanes x bf16x8 (uint4) = 256B row per load instruction slice.
__global__ __launch_bounds__(256) void arc_score(const int2* __restrict__ arcs,
                                                 const unsigned short* __restrict__ UV,
                                                 const float* __restrict__ W2,
                                                 const float* __restrict__ b2,
                                                 float* __restrict__ out) {
    const int tid = threadIdx.x;
    const int sub = tid & 15;
    const int gq = blockIdx.x * 16 + (tid >> 4);   // global quarter-wave id
    const int eb = sub * 8;

    float w2v[8];
    #pragma unroll
    for (int i = 0; i < 8; i++) w2v[i] = W2[eb + i];
    const float b2s = b2[0];

    const long stride = (long)gridDim.x * 32;   // 16 quarters/block * 2 arcs
    for (long a0 = (long)gq * 2; a0 < N_ARCS; a0 += stride) {
        int2 s0 = arcs[a0];
        int2 s1 = arcs[a0 + 1];
        uint4 u0 = *(const uint4*)(UV + (long)s0.x * 256 + eb);
        uint4 v0 = *(const uint4*)(UV + (long)s0.y * 256 + 128 + eb);
        uint4 u1 = *(const uint4*)(UV + (long)s1.x * 256 + eb);
        uint4 v1 = *(const uint4*)(UV + (long)s1.y * 256 + 128 + eb);

        float p0 = 0.f, p1 = 0.f;
        const unsigned* uw0 = (const unsigned*)&u0;
        const unsigned* vw0 = (const unsigned*)&v0;
        const unsigned* uw1 = (const unsigned*)&u1;
        const unsigned* vw1 = (const unsigned*)&v1;
        #pragma unroll
        for (int i = 0; i < 4; i++) {
            union { unsigned u; float f; } fu, fv;
            // low halves
            fu.u = uw0[i] << 16; fv.u = vw0[i] << 16;
            p0 = fmaf(fmaxf(fu.f + fv.f, 0.f), w2v[2 * i], p0);
            fu.u = uw1[i] << 16; fv.u = vw1[i] << 16;
            p1 = fmaf(fmaxf(fu.f + fv.f, 0.f), w2v[2 * i], p1);
            // high halves (free decode: mask)
            fu.u = uw0[i] & 0xffff0000u; fv.u = vw0[i] & 0xffff0000u;
            p0 = fmaf(fmaxf(fu.f + fv.f, 0.f), w2v[2 * i + 1], p0);
            fu.u = uw1[i] & 0xffff0000u; fv.u = vw1[i] & 0xffff0000u;
            p1 = fmaf(fmaxf(fu.f + fv.f, 0.f), w2v[2 * i + 1], p1);
        }
        #pragma unroll
        for (int o = 8; o >= 1; o >>= 1) {
            p0 += __shfl_xor(p0, o);
            p1 += __shfl_xor(p1, o);
        }
        if (sub == 0) {
            out[a0] = p0 + b2s;
            out[a0 + 1] = p1 + b2s;
        }
    }
}

extern "C" void kernel_launch(void* const* d_in, const int* in_sizes, int n_in,
                              void* d_out, int out_size, void* d_ws, size_t ws_size,
                              hipStream_t stream) {
    const float* z  = (const float*)d_in[0];
    const int2* arcs = (const int2*)d_in[1];
    const float* W1 = (const float*)d_in[2];
    const float* b1 = (const float*)d_in[3];
    const float* W2 = (const float*)d_in[4];
    const float* b2 = (const float*)d_in[5];
    float* out = (float*)d_out;

    unsigned short* UV = (unsigned short*)d_ws;   // bf16 [100000][256] = 51.2 MB

    hipLaunchKernelGGL(gemm_uv, dim3((N_NODES + 127) / 128), dim3(256), 0, stream,
                       z, W1, b1, UV);
    hipLaunchKernelGGL(arc_score, dim3(2048), dim3(256), 0, stream,
                       arcs, UV, W2, b2, out);
}

// Round 4
// 197.767 us; speedup vs baseline: 1.0376x; 1.0376x over previous
//
#include <hip/hip_runtime.h>
#include <hip/hip_bf16.h>

#define N_NODES 100000
#define HIDDEN 128
#define N_ARCS 1000000

typedef __attribute__((ext_vector_type(8))) short bf16x8;
typedef __attribute__((ext_vector_type(4))) float f32x4;

__device__ __forceinline__ unsigned short f2bf(float v) {
    union { float f; unsigned ui; } c; c.f = v;
    unsigned lsb = (c.ui >> 16) & 1;
    return (unsigned short)((c.ui + 0x7fffu + lsb) >> 16);
}

__device__ __forceinline__ unsigned pk2(float lo, float hi) {
    __hip_bfloat162 b = __float22bfloat162_rn(make_float2(lo, hi));
    union { __hip_bfloat162 b; unsigned u; } c; c.b = b; return c.u;
}

__device__ __forceinline__ uint4 pack8(const float4 a, const float4 b) {
    uint4 r;
    r.x = pk2(a.x, a.y);
    r.y = pk2(a.z, a.w);
    r.z = pk2(b.x, b.y);
    r.w = pk2(b.z, b.w);
    return r;
}

// UV[node][0:128] = z @ W1[:,:128]^T + b1 ; UV[node][128:256] = z @ W1[:,128:]^T
// 64-row x 128-col tiles, grid (1563, 2). 48 KB LDS -> 3 blocks/CU; single
// compute barrier. fp32 in, bf16 MFMA, bf16 UV out.
__global__ __launch_bounds__(256) void gemm_uv(const float* __restrict__ z,
                                               const float* __restrict__ W1,
                                               const float* __restrict__ b1,
                                               unsigned short* __restrict__ UV) {
    __shared__ unsigned short As[64 * 128];    // 16 KB
    __shared__ unsigned short Bs[128 * 128];   // 32 KB
    const int tid = threadIdx.x;
    const int m0 = blockIdx.x * 64;
    const int c0 = blockIdx.y * 128;

    // Stage A (64 z-rows, fp32->bf16), 16B granules, XOR swizzle g^(row&15).
    #pragma unroll
    for (int it = 0; it < 4; it++) {
        int i = tid + it * 256;
        int row = i >> 4, g = i & 15;
        int node = m0 + row;
        uint4 p = make_uint4(0u, 0u, 0u, 0u);
        if (node < N_NODES) {
            const float4* s = (const float4*)(z + (long)node * 128 + g * 8);
            p = pack8(s[0], s[1]);
        }
        ((uint4*)As)[row * 16 + (g ^ (row & 15))] = p;
    }
    // Stage B: Bs[n][k] = W1[n][c0+k], same swizzle.
    #pragma unroll
    for (int it = 0; it < 8; it++) {
        int i = tid + it * 256;
        int row = i >> 4, g = i & 15;
        const float4* s = (const float4*)(W1 + (long)row * 256 + c0 + g * 8);
        ((uint4*)Bs)[row * 16 + (g ^ (row & 15))] = pack8(s[0], s[1]);
    }
    __syncthreads();

    const int lane = tid & 63;
    const int wave = tid >> 6;       // wave w: rows [w*16, w*16+16), all 128 cols
    const int l16 = lane & 15;
    const int quad = lane >> 4;
    const int arow = wave * 16 + l16;

    f32x4 acc[8] = {};
    #pragma unroll
    for (int ks = 0; ks < 4; ks++) {
        const int gb = ks * 4 + quad;
        const bf16x8 a = *(const bf16x8*)&As[arow * 128 + ((gb ^ l16) << 3)];
        #pragma unroll
        for (int nt = 0; nt < 8; nt++) {
            const bf16x8 b = *(const bf16x8*)&Bs[(nt * 16 + l16) * 128 + ((gb ^ l16) << 3)];
            acc[nt] = __builtin_amdgcn_mfma_f32_16x16x32_bf16(a, b, acc[nt], 0, 0, 0);
        }
    }

    // C/D: col = lane&15, row = quad*4 + reg. Fold b1 into the U half.
    #pragma unroll
    for (int nt = 0; nt < 8; nt++) {
        int gcol = c0 + nt * 16 + l16;
        float bias = (blockIdx.y == 0) ? b1[gcol] : 0.0f;
        #pragma unroll
        for (int r = 0; r < 4; r++) {
            int grow = m0 + wave * 16 + quad * 4 + r;
            if (grow < N_NODES)
                UV[(long)grow * 256 + gcol] = f2bf(acc[nt][r] + bias);
        }
    }
}

// One arc-pair per 16-lane quarter-wave, software-pipelined 1 stage deep:
// iteration i issues gathers for i+1 and prefetches indices for i+2.
__global__ __launch_bounds__(256) void arc_score(const int2* __restrict__ arcs,
                                                 const unsigned short* __restrict__ UV,
                                                 const float* __restrict__ W2,
                                                 const float* __restrict__ b2,
                                                 float* __restrict__ out) {
    const int tid = threadIdx.x;
    const int sub = tid & 15;
    const int gq = blockIdx.x * 16 + (tid >> 4);
    const int eb = sub * 8;

    float w2v[8];
    #pragma unroll
    for (int i = 0; i < 8; i++) w2v[i] = W2[eb + i];
    const float b2s = b2[0];

    const int4* arcs4 = (const int4*)arcs;   // two int2 arcs per int4
    const long stride = (long)gridDim.x * 32;
    const long limp = (long)(N_ARCS - 2) >> 1;   // last valid pair index

    long a = (long)gq * 2;
    long p0i = a >> 1; if (p0i > limp) p0i = limp;
    int4 i0 = arcs4[p0i];
    uint4 u0 = *(const uint4*)(UV + (long)i0.x * 256 + eb);
    uint4 v0 = *(const uint4*)(UV + (long)i0.y * 256 + 128 + eb);
    uint4 u1 = *(const uint4*)(UV + (long)i0.z * 256 + eb);
    uint4 v1 = *(const uint4*)(UV + (long)i0.w * 256 + 128 + eb);
    long p1i = (a + stride) >> 1; if (p1i > limp) p1i = limp;
    int4 i1 = arcs4[p1i];

    while (true) {
        const long an = a + stride;
        // issue next iteration's gathers (indices ready; clamped so always valid)
        uint4 nu0 = *(const uint4*)(UV + (long)i1.x * 256 + eb);
        uint4 nv0 = *(const uint4*)(UV + (long)i1.y * 256 + 128 + eb);
        uint4 nu1 = *(const uint4*)(UV + (long)i1.z * 256 + eb);
        uint4 nv1 = *(const uint4*)(UV + (long)i1.w * 256 + 128 + eb);
        // prefetch indices two iterations ahead
        long p2i = (an + stride) >> 1; if (p2i > limp) p2i = limp;
        int4 i2 = arcs4[p2i];

        // compute current pair
        float s0 = 0.f, s1 = 0.f;
        const unsigned* uw0 = (const unsigned*)&u0;
        const unsigned* vw0 = (const unsigned*)&v0;
        const unsigned* uw1 = (const unsigned*)&u1;
        const unsigned* vw1 = (const unsigned*)&v1;
        #pragma unroll
        for (int i = 0; i < 4; i++) {
            union { unsigned u; float f; } fu, fv;
            fu.u = uw0[i] << 16; fv.u = vw0[i] << 16;
            s0 = fmaf(fmaxf(fu.f + fv.f, 0.f), w2v[2 * i], s0);
            fu.u = uw1[i] << 16; fv.u = vw1[i] << 16;
            s1 = fmaf(fmaxf(fu.f + fv.f, 0.f), w2v[2 * i], s1);
            fu.u = uw0[i] & 0xffff0000u; fv.u = vw0[i] & 0xffff0000u;
            s0 = fmaf(fmaxf(fu.f + fv.f, 0.f), w2v[2 * i + 1], s0);
            fu.u = uw1[i] & 0xffff0000u; fv.u = vw1[i] & 0xffff0000u;
            s1 = fmaf(fmaxf(fu.f + fv.f, 0.f), w2v[2 * i + 1], s1);
        }
        #pragma unroll
        for (int o = 8; o >= 1; o >>= 1) {
            s0 += __shfl_xor(s0, o);
            s1 += __shfl_xor(s1, o);
        }
        if (sub == 0) {
            out[a] = s0 + b2s;          // a < N_ARCS guaranteed in-loop
            out[a + 1] = s1 + b2s;
        }

        if (an >= N_ARCS) break;        // divergence only at quarter granularity
        a = an;
        u0 = nu0; v0 = nv0; u1 = nu1; v1 = nv1;
        i1 = i2;
    }
}

extern "C" void kernel_launch(void* const* d_in, const int* in_sizes, int n_in,
                              void* d_out, int out_size, void* d_ws, size_t ws_size,
                              hipStream_t stream) {
    const float* z  = (const float*)d_in[0];
    const int2* arcs = (const int2*)d_in[1];
    const float* W1 = (const float*)d_in[2];
    const float* b1 = (const float*)d_in[3];
    const float* W2 = (const float*)d_in[4];
    const float* b2 = (const float*)d_in[5];
    float* out = (float*)d_out;

    unsigned short* UV = (unsigned short*)d_ws;   // bf16 [100000][256] = 51.2 MB

    hipLaunchKernelGGL(gemm_uv, dim3((N_NODES + 63) / 64, 2), dim3(256), 0, stream,
                       z, W1, b1, UV);
    hipLaunchKernelGGL(arc_score, dim3(2048), dim3(256), 0, stream,
                       arcs, UV, W2, b2, out);
}

// Round 5
// 160.339 us; speedup vs baseline: 1.2798x; 1.2334x over previous
//
#include <hip/hip_runtime.h>
#include <hip/hip_bf16.h>

#define N_NODES 100000
#define NODES_PAD 100096   // pad so epilogue float4/byte stores need no guards
#define N_ARCS 1000000

typedef __attribute__((ext_vector_type(8))) short bf16x8;
typedef __attribute__((ext_vector_type(4))) float f32x4;

__device__ __forceinline__ unsigned pk2(float lo, float hi) {
    __hip_bfloat162 b = __float22bfloat162_rn(make_float2(lo, hi));
    union { __hip_bfloat162 b; unsigned u; } c; c.b = b; return c.u;
}

__device__ __forceinline__ uint4 pack8(const float4 a, const float4 b) {
    uint4 r;
    r.x = pk2(a.x, a.y);
    r.y = pk2(a.z, a.w);
    r.z = pk2(b.x, b.y);
    r.w = pk2(b.z, b.w);
    return r;
}

// Persistent GEMM + fused int8 row quantization.
// y-half 0: U = z@W1[:,:128]^T + b1 ; y-half 1: V = z@W1[:,128:]^T.
// Output: UVq[node][0:128]=uint8(U), [128:256]=uint8(V), biased by +128;
// scl[y*NODES_PAD + node] = per-row dequant scale (rowmax/127).
__global__ __launch_bounds__(256) void gemm_uv_q(const float* __restrict__ z,
                                                 const float* __restrict__ W1,
                                                 const float* __restrict__ b1,
                                                 unsigned char* __restrict__ UVq,
                                                 float* __restrict__ scl) {
    __shared__ unsigned short As[64 * 128];    // 16 KB
    __shared__ unsigned short Bs[128 * 128];   // 32 KB
    const int tid = threadIdx.x;
    const int y = blockIdx.y;
    const int c0 = y * 128;

    // Stage this half of W1 ONCE (persistent block). XOR swizzle g^(row&15).
    #pragma unroll
    for (int it = 0; it < 8; it++) {
        int i = tid + it * 256;
        int row = i >> 4, g = i & 15;
        const float4* s = (const float4*)(W1 + (long)row * 256 + c0 + g * 8);
        ((uint4*)Bs)[row * 16 + (g ^ (row & 15))] = pack8(s[0], s[1]);
    }

    const int lane = tid & 63;
    const int wave = tid >> 6;
    const int l16 = lane & 15;
    const int quad = lane >> 4;

    float bias[8];
    #pragma unroll
    for (int nt = 0; nt < 8; nt++)
        bias[nt] = (y == 0) ? b1[nt * 16 + l16] : 0.0f;   // fold b1 into U pre-quant

    float* sclh = scl + (long)y * NODES_PAD;

    for (int m0 = blockIdx.x * 64; m0 < N_NODES; m0 += gridDim.x * 64) {
        // Stage A: 64 z-rows, fp32 -> bf16 packed.
        #pragma unroll
        for (int it = 0; it < 4; it++) {
            int i = tid + it * 256;
            int row = i >> 4, g = i & 15;
            int node = m0 + row;
            uint4 p = make_uint4(0u, 0u, 0u, 0u);
            if (node < N_NODES) {
                const float4* s = (const float4*)(z + (long)node * 128 + g * 8);
                p = pack8(s[0], s[1]);
            }
            ((uint4*)As)[row * 16 + (g ^ (row & 15))] = p;
        }
        __syncthreads();

        const int arow = wave * 16 + l16;
        f32x4 acc[8] = {};
        #pragma unroll
        for (int ks = 0; ks < 4; ks++) {
            const int gb = ks * 4 + quad;
            const bf16x8 a = *(const bf16x8*)&As[arow * 128 + ((gb ^ l16) << 3)];
            #pragma unroll
            for (int nt = 0; nt < 8; nt++) {
                const bf16x8 b = *(const bf16x8*)&Bs[(nt * 16 + l16) * 128 + ((gb ^ l16) << 3)];
                acc[nt] = __builtin_amdgcn_mfma_f32_16x16x32_bf16(a, b, acc[nt], 0, 0, 0);
            }
        }

        // Epilogue: bias add, per-row absmax (16-lane butterfly), quantize.
        // C/D: col = nt*16 + (lane&15), row = quad*4 + reg.
        float m[4] = {0.f, 0.f, 0.f, 0.f};
        #pragma unroll
        for (int nt = 0; nt < 8; nt++)
            #pragma unroll
            for (int r = 0; r < 4; r++) {
                acc[nt][r] += bias[nt];
                m[r] = fmaxf(m[r], fabsf(acc[nt][r]));
            }
        #pragma unroll
        for (int o = 1; o <= 8; o <<= 1)
            #pragma unroll
            for (int r = 0; r < 4; r++)
                m[r] = fmaxf(m[r], __shfl_xor(m[r], o));

        const int rbase = m0 + wave * 16 + quad * 4;
        float inv[4];
        #pragma unroll
        for (int r = 0; r < 4; r++) {
            m[r] = fmaxf(m[r], 1e-30f);
            inv[r] = 127.0f * __builtin_amdgcn_rcpf(m[r]);
        }
        if (l16 == 0)
            *(float4*)(sclh + rbase) = make_float4(m[0] * (1.f / 127.f), m[1] * (1.f / 127.f),
                                                   m[2] * (1.f / 127.f), m[3] * (1.f / 127.f));
        unsigned char* wp = UVq + (long)rbase * 256 + c0 + l16;
        #pragma unroll
        for (int r = 0; r < 4; r++)
            #pragma unroll
            for (int nt = 0; nt < 8; nt++) {
                int qi = __float2int_rn(acc[nt][r] * inv[r]) + 128;   // biased uint8
                wp[(long)r * 256 + nt * 16] = (unsigned char)qi;
            }
        __syncthreads();   // all waves done reading As before restage
    }
}

// One arc-pair per 16-lane quarter-wave. int8 rows (128 B each), per-row scales.
// relu(sU*qU + sV*qV) = sU * relu((gu-C) + r*gv), r=sV/sU, C=128*(1+r).
__global__ __launch_bounds__(256) void arc_score(const int4* __restrict__ arcs4,
                                                 const unsigned char* __restrict__ UVq,
                                                 const float* __restrict__ scl,
                                                 const float* __restrict__ W2,
                                                 const float* __restrict__ b2,
                                                 float* __restrict__ out) {
    const int tid = threadIdx.x;
    const int sub = tid & 15;
    const int gq = blockIdx.x * 16 + (tid >> 4);
    const int eb = sub * 8;

    float w2v[8];
    #pragma unroll
    for (int i = 0; i < 8; i++) w2v[i] = W2[eb + i];
    const float b2s = b2[0];
    const float* sclV = scl + NODES_PAD;

    const long stride = (long)gridDim.x * 32;
    for (long a = (long)gq * 2; a < N_ARCS; a += stride) {
        int4 sd = arcs4[a >> 1];
        const uint2 qu0 = *(const uint2*)(UVq + (long)sd.x * 256 + eb);
        const uint2 qv0 = *(const uint2*)(UVq + (long)sd.y * 256 + 128 + eb);
        const uint2 qu1 = *(const uint2*)(UVq + (long)sd.z * 256 + eb);
        const uint2 qv1 = *(const uint2*)(UVq + (long)sd.w * 256 + 128 + eb);
        const float sU0 = scl[sd.x], sV0 = sclV[sd.y];
        const float sU1 = scl[sd.z], sV1 = sclV[sd.w];
        const float r0 = sV0 * __builtin_amdgcn_rcpf(sU0);
        const float r1 = sV1 * __builtin_amdgcn_rcpf(sU1);
        const float C0 = 128.0f * (1.0f + r0);
        const float C1 = 128.0f * (1.0f + r1);

        float p0 = 0.f, p1 = 0.f;
        const unsigned uw0[2] = {qu0.x, qu0.y}, vw0[2] = {qv0.x, qv0.y};
        const unsigned uw1[2] = {qu1.x, qu1.y}, vw1[2] = {qv1.x, qv1.y};
        #pragma unroll
        for (int w = 0; w < 2; w++) {
            #pragma unroll
            for (int i = 0; i < 4; i++) {
                float gu0 = (float)((uw0[w] >> (8 * i)) & 0xffu);   // v_cvt_f32_ubyte
                float gv0 = (float)((vw0[w] >> (8 * i)) & 0xffu);
                float h0 = fmaf(gv0, r0, gu0 - C0);
                p0 = fmaf(fmaxf(h0, 0.f), w2v[w * 4 + i], p0);
                float gu1 = (float)((uw1[w] >> (8 * i)) & 0xffu);
                float gv1 = (float)((vw1[w] >> (8 * i)) & 0xffu);
                float h1 = fmaf(gv1, r1, gu1 - C1);
                p1 = fmaf(fmaxf(h1, 0.f), w2v[w * 4 + i], p1);
            }
        }
        #pragma unroll
        for (int o = 8; o >= 1; o >>= 1) {
            p0 += __shfl_xor(p0, o);
            p1 += __shfl_xor(p1, o);
        }
        if (sub == 0) {
            out[a] = fmaf(sU0, p0, b2s);
            out[a + 1] = fmaf(sU1, p1, b2s);
        }
    }
}

extern "C" void kernel_launch(void* const* d_in, const int* in_sizes, int n_in,
                              void* d_out, int out_size, void* d_ws, size_t ws_size,
                              hipStream_t stream) {
    const float* z  = (const float*)d_in[0];
    const int4* arcs4 = (const int4*)d_in[1];
    const float* W1 = (const float*)d_in[2];
    const float* b1 = (const float*)d_in[3];
    const float* W2 = (const float*)d_in[4];
    const float* b2 = (const float*)d_in[5];
    float* out = (float*)d_out;

    // ws: UVq uint8 [NODES_PAD][256] = 25.6 MB, then scales 2*[NODES_PAD] fp32.
    unsigned char* UVq = (unsigned char*)d_ws;
    float* scl = (float*)((char*)d_ws + (size_t)NODES_PAD * 256);

    hipLaunchKernelGGL(gemm_uv_q, dim3(384, 2), dim3(256), 0, stream,
                       z, W1, b1, UVq, scl);
    hipLaunchKernelGGL(arc_score, dim3(2048), dim3(256), 0, stream,
                       arcs4, UVq, scl, W2, b2, out);
}

// Round 6
// 145.036 us; speedup vs baseline: 1.4148x; 1.1055x over previous
//
#include <hip/hip_runtime.h>
#include <hip/hip_bf16.h>

#define N_NODES 100000
#define NODES_PAD 100096
#define N_ARCS 1000000

typedef __attribute__((ext_vector_type(8))) short bf16x8;
typedef __attribute__((ext_vector_type(4))) float f32x4;

__device__ __forceinline__ unsigned pk2(float lo, float hi) {
    __hip_bfloat162 b = __float22bfloat162_rn(make_float2(lo, hi));
    union { __hip_bfloat162 b; unsigned u; } c; c.b = b; return c.u;
}

__device__ __forceinline__ uint4 pack8(const float4 a, const float4 b) {
    uint4 r;
    r.x = pk2(a.x, a.y);
    r.y = pk2(a.z, a.w);
    r.z = pk2(b.x, b.y);
    r.w = pk2(b.z, b.w);
    return r;
}

// Persistent GEMM + fused int8 row quantization.
// y=0: U = z@W1[:,:128]^T + b1 ; y=1: V = z@W1[:,128:]^T.
// UVq row bytes are PERMUTED: byte p of a 128-B half-row holds col (p&7)*16 + (p>>3).
// This makes the epilogue store coalesced dwordx2; consumer loads W2 permuted.
__global__ __launch_bounds__(256) void gemm_uv_q(const float* __restrict__ z,
                                                 const float* __restrict__ W1,
                                                 const float* __restrict__ b1,
                                                 unsigned char* __restrict__ UVq,
                                                 float* __restrict__ scl) {
    __shared__ unsigned short As[64 * 128];    // 16 KB
    __shared__ unsigned short Bs[128 * 128];   // 32 KB
    const int tid = threadIdx.x;
    const int y = blockIdx.y;
    const int c0 = y * 128;

    #pragma unroll
    for (int it = 0; it < 8; it++) {
        int i = tid + it * 256;
        int row = i >> 4, g = i & 15;
        const float4* s = (const float4*)(W1 + (long)row * 256 + c0 + g * 8);
        ((uint4*)Bs)[row * 16 + (g ^ (row & 15))] = pack8(s[0], s[1]);
    }

    const int lane = tid & 63;
    const int wave = tid >> 6;
    const int l16 = lane & 15;
    const int quad = lane >> 4;

    float bias[8];
    #pragma unroll
    for (int nt = 0; nt < 8; nt++)
        bias[nt] = (y == 0) ? b1[nt * 16 + l16] : 0.0f;

    float* sclh = scl + (long)y * NODES_PAD;

    for (int m0 = blockIdx.x * 64; m0 < N_NODES; m0 += gridDim.x * 64) {
        #pragma unroll
        for (int it = 0; it < 4; it++) {
            int i = tid + it * 256;
            int row = i >> 4, g = i & 15;
            int node = m0 + row;
            uint4 p = make_uint4(0u, 0u, 0u, 0u);
            if (node < N_NODES) {
                const float4* s = (const float4*)(z + (long)node * 128 + g * 8);
                p = pack8(s[0], s[1]);
            }
            ((uint4*)As)[row * 16 + (g ^ (row & 15))] = p;
        }
        __syncthreads();

        const int arow = wave * 16 + l16;
        f32x4 acc[8] = {};
        #pragma unroll
        for (int ks = 0; ks < 4; ks++) {
            const int gb = ks * 4 + quad;
            const bf16x8 a = *(const bf16x8*)&As[arow * 128 + ((gb ^ l16) << 3)];
            #pragma unroll
            for (int nt = 0; nt < 8; nt++) {
                const bf16x8 b = *(const bf16x8*)&Bs[(nt * 16 + l16) * 128 + ((gb ^ l16) << 3)];
                acc[nt] = __builtin_amdgcn_mfma_f32_16x16x32_bf16(a, b, acc[nt], 0, 0, 0);
            }
        }

        // Epilogue: bias, row absmax (16-lane butterfly), quantize, packed store.
        float m[4] = {0.f, 0.f, 0.f, 0.f};
        #pragma unroll
        for (int nt = 0; nt < 8; nt++)
            #pragma unroll
            for (int r = 0; r < 4; r++) {
                acc[nt][r] += bias[nt];
                m[r] = fmaxf(m[r], fabsf(acc[nt][r]));
            }
        #pragma unroll
        for (int o = 1; o <= 8; o <<= 1)
            #pragma unroll
            for (int r = 0; r < 4; r++)
                m[r] = fmaxf(m[r], __shfl_xor(m[r], o));

        const int rbase = m0 + wave * 16 + quad * 4;
        float inv[4];
        #pragma unroll
        for (int r = 0; r < 4; r++) {
            m[r] = fmaxf(m[r], 1e-30f);
            inv[r] = 127.0f * __builtin_amdgcn_rcpf(m[r]);
        }
        if (l16 == 0)
            *(float4*)(sclh + rbase) = make_float4(m[0] * (1.f / 127.f), m[1] * (1.f / 127.f),
                                                   m[2] * (1.f / 127.f), m[3] * (1.f / 127.f));
        // Packed permuted store: byte p = l16*8 + nt holds col nt*16 + l16.
        #pragma unroll
        for (int r = 0; r < 4; r++) {
            unsigned lo = 0, hi = 0;
            #pragma unroll
            for (int nt = 0; nt < 4; nt++) {
                unsigned q = (unsigned)__float2int_rn(fmaf(acc[nt][r], inv[r], 128.f));
                lo |= (q & 0xffu) << (8 * nt);
            }
            #pragma unroll
            for (int nt = 4; nt < 8; nt++) {
                unsigned q = (unsigned)__float2int_rn(fmaf(acc[nt][r], inv[r], 128.f));
                hi |= (q & 0xffu) << (8 * (nt - 4));
            }
            *(uint2*)(UVq + (long)(rbase + r) * 256 + c0 + l16 * 8) = make_uint2(lo, hi);
        }
        __syncthreads();
    }
}

// One arc-pair per 8-lane group (uint4 = 16 elems/lane), software-pipelined.
// relu trick: out = sU*(sum_j max(h_j, C)*w2_j - C*sumW2) + b2,
// h_j = gu_j + r*gv_j, r = sV/sU, C = 128*(1+r).
__global__ __launch_bounds__(256) void arc_score(const int4* __restrict__ arcs4,
                                                 const unsigned char* __restrict__ UVq,
                                                 const float* __restrict__ scl,
                                                 const float* __restrict__ W2,
                                                 const float* __restrict__ b2,
                                                 float* __restrict__ out) {
    const int tid = threadIdx.x;
    const int sub = tid & 7;
    const int gq = blockIdx.x * 32 + (tid >> 3);
    const int eb = sub * 16;

    // Permuted W2: byte p of half-row -> col (p&7)*16 + (p>>3); lane covers p=eb..eb+15.
    float w2v[16], w2s = 0.f;
    #pragma unroll
    for (int i = 0; i < 16; i++) {
        int col = ((i & 7) << 4) + (sub << 1) + (i >> 3);
        w2v[i] = W2[col];
        w2s += w2v[i];
    }
    const float b2s = b2[0];
    const float* sclV = scl + NODES_PAD;

    const long stride = (long)gridDim.x * 64;   // 32 groups/block * 2 arcs
    const long limp = (long)(N_ARCS - 2) >> 1;

    long a = (long)gq * 2;
    int4 i0 = arcs4[a >> 1];
    uint4 u0 = *(const uint4*)(UVq + (long)i0.x * 256 + eb);
    uint4 v0 = *(const uint4*)(UVq + (long)i0.y * 256 + 128 + eb);
    uint4 u1 = *(const uint4*)(UVq + (long)i0.z * 256 + eb);
    uint4 v1 = *(const uint4*)(UVq + (long)i0.w * 256 + 128 + eb);
    float sU0 = scl[i0.x], sV0 = sclV[i0.y];
    float sU1 = scl[i0.z], sV1 = sclV[i0.w];
    long p1i = (a + stride) >> 1; if (p1i > limp) p1i = limp;
    int4 i1 = arcs4[p1i];

    while (true) {
        const long an = a + stride;
        // next iteration's gathers (clamped indices, always valid)
        uint4 nu0 = *(const uint4*)(UVq + (long)i1.x * 256 + eb);
        uint4 nv0 = *(const uint4*)(UVq + (long)i1.y * 256 + 128 + eb);
        uint4 nu1 = *(const uint4*)(UVq + (long)i1.z * 256 + eb);
        uint4 nv1 = *(const uint4*)(UVq + (long)i1.w * 256 + 128 + eb);
        float nsU0 = scl[i1.x], nsV0 = sclV[i1.y];
        float nsU1 = scl[i1.z], nsV1 = sclV[i1.w];
        long p2i = (an + stride) >> 1; if (p2i > limp) p2i = limp;
        int4 i2 = arcs4[p2i];

        const float r0 = sV0 * __builtin_amdgcn_rcpf(sU0);
        const float r1 = sV1 * __builtin_amdgcn_rcpf(sU1);
        const float C0 = fmaf(128.f, r0, 128.f);
        const float C1 = fmaf(128.f, r1, 128.f);

        float p0 = 0.f, p1 = 0.f;
        const unsigned* uw0 = (const unsigned*)&u0;
        const unsigned* vw0 = (const unsigned*)&v0;
        const unsigned* uw1 = (const unsigned*)&u1;
        const unsigned* vw1 = (const unsigned*)&v1;
        #pragma unroll
        for (int w = 0; w < 4; w++) {
            #pragma unroll
            for (int j = 0; j < 4; j++) {
                float gu0 = (float)((uw0[w] >> (8 * j)) & 0xffu);
                float gv0 = (float)((vw0[w] >> (8 * j)) & 0xffu);
                p0 = fmaf(fmaxf(fmaf(gv0, r0, gu0), C0), w2v[w * 4 + j], p0);
                float gu1 = (float)((uw1[w] >> (8 * j)) & 0xffu);
                float gv1 = (float)((vw1[w] >> (8 * j)) & 0xffu);
                p1 = fmaf(fmaxf(fmaf(gv1, r1, gu1), C1), w2v[w * 4 + j], p1);
            }
        }
        p0 = fmaf(-C0, w2s, p0);
        p1 = fmaf(-C1, w2s, p1);
        #pragma unroll
        for (int o = 4; o >= 1; o >>= 1) {
            p0 += __shfl_xor(p0, o);
            p1 += __shfl_xor(p1, o);
        }
        if (sub == 0) {
            out[a] = fmaf(sU0, p0, b2s);
            out[a + 1] = fmaf(sU1, p1, b2s);
        }

        if (an >= N_ARCS) break;
        a = an;
        u0 = nu0; v0 = nv0; u1 = nu1; v1 = nv1;
        sU0 = nsU0; sV0 = nsV0; sU1 = nsU1; sV1 = nsV1;
        i1 = i2;
    }
}

extern "C" void kernel_launch(void* const* d_in, const int* in_sizes, int n_in,
                              void* d_out, int out_size, void* d_ws, size_t ws_size,
                              hipStream_t stream) {
    const float* z  = (const float*)d_in[0];
    const int4* arcs4 = (const int4*)d_in[1];
    const float* W1 = (const float*)d_in[2];
    const float* b1 = (const float*)d_in[3];
    const float* W2 = (const float*)d_in[4];
    const float* b2 = (const float*)d_in[5];
    float* out = (float*)d_out;

    unsigned char* UVq = (unsigned char*)d_ws;                     // 25.6 MB
    float* scl = (float*)((char*)d_ws + (size_t)NODES_PAD * 256);  // 2*NODES_PAD f32

    hipLaunchKernelGGL(gemm_uv_q, dim3(384, 2), dim3(256), 0, stream,
                       z, W1, b1, UVq, scl);
    hipLaunchKernelGGL(arc_score, dim3(2048), dim3(256), 0, stream,
                       arcs4, UVq, scl, W2, b2, out);
}